// Round 1
// baseline (421.613 us; speedup 1.0000x reference)
//
#include <hip/hip_runtime.h>
#include <stdint.h>

typedef unsigned short u16;
typedef __attribute__((ext_vector_type(8))) short bf16x8;
typedef __attribute__((ext_vector_type(4))) float f32x4;
typedef __attribute__((ext_vector_type(4))) unsigned short u16x4;

#define AS1 __attribute__((address_space(1)))
#define AS3 __attribute__((address_space(3)))

static __device__ __forceinline__ u16 f2bf(float f) {
  union { float f; uint32_t u; } c; c.f = f;
  return (u16)((c.u + 0x7FFFu + ((c.u >> 16) & 1u)) >> 16);
}

// ---- x (f32) -> bf16, 4 elems/thread ----
__global__ __launch_bounds__(256) void k_convert_x(const float* __restrict__ x,
                                                   u16* __restrict__ abf) {
  int i = blockIdx.x * 256 + threadIdx.x;
  float4 v = reinterpret_cast<const float4*>(x)[i];
  u16x4 o = { f2bf(v.x), f2bf(v.y), f2bf(v.z), f2bf(v.w) };
  reinterpret_cast<u16x4*>(abf)[i] = o;
}

// ---- w[t][d][e] f32 -> bt[t][e][d] bf16 (transpose, 64x64 tiles) ----
__global__ __launch_bounds__(256) void k_transpose_w(const float* __restrict__ w,
                                                     u16* __restrict__ bt) {
  __shared__ u16 tile[64][65];
  const int t = blockIdx.z;
  const int e0 = blockIdx.x * 64, d0 = blockIdx.y * 64;
  const int tx = threadIdx.x & 63, ty = threadIdx.x >> 6;
  const float* wp = w + ((size_t)t << 20);
  u16* bp = bt + ((size_t)t << 20);
  for (int rr = 0; rr < 16; ++rr) {
    int r = rr * 4 + ty;
    tile[r][tx] = f2bf(wp[(size_t)(d0 + r) * 1024 + (e0 + tx)]);
  }
  __syncthreads();
  for (int rr = 0; rr < 16; ++rr) {
    int r = rr * 4 + ty;
    bp[(size_t)(e0 + r) * 1024 + (d0 + tx)] = tile[tx][r];
  }
}

// ---- W2[t][d][k] = sum_e w[t][d][e] * ww[t][e][k] ----
__global__ __launch_bounds__(256) void k_w2(const float* __restrict__ w,
                                            const float* __restrict__ ww,
                                            float* __restrict__ w2) {
  const int dl = threadIdx.x >> 4, kk = threadIdx.x & 15;
  const int t = blockIdx.x >> 6;
  const int d = ((blockIdx.x & 63) << 4) + dl;
  const float* wr = w + ((size_t)t << 20) + ((size_t)d << 10);
  const float* wp = ww + (t << 14) + kk;
  float acc = 0.f;
#pragma unroll 8
  for (int e = 0; e < 1024; ++e) acc = fmaf(wr[e], wp[e << 4], acc);
  w2[(((size_t)t << 10) + (size_t)d) * 16 + kk] = acc;
}

// ---- x_read/x_write -> logits -> softmax -> att[n][8] (16 rows/block) ----
__global__ __launch_bounds__(256) void k_att(const float* __restrict__ x,
                                             const float* __restrict__ wread,
                                             const float* __restrict__ w2,
                                             float* __restrict__ att) {
  __shared__ float res[16][144];
  __shared__ float lg[16][8];
  const int row0 = blockIdx.x * 16;
  for (int it = 0; it < 9; ++it) {
    int idx = it * 256 + threadIdx.x;            // 0..2303 = 16 rows x 144 cols
    int r = idx / 144, c = idx - r * 144;
    const float* xp = x + ((size_t)(row0 + r) << 10);
    const float* bp2;
    if (c < 16) bp2 = wread + c;                 // w_read[d][c], stride 16
    else { int tt = (c - 16) >> 4, k2 = (c - 16) & 15; bp2 = w2 + (tt << 14) + k2; }
    float acc = 0.f;
#pragma unroll 8
    for (int d = 0; d < 1024; ++d) acc = fmaf(xp[d], bp2[d << 4], acc);
    res[r][c] = acc;
  }
  __syncthreads();
  if (threadIdx.x < 128) {
    int r = threadIdx.x >> 3, tt = threadIdx.x & 7;
    float acc = 0.f;
#pragma unroll
    for (int k2 = 0; k2 < 16; ++k2) acc = fmaf(res[r][k2], res[r][16 + tt * 16 + k2], acc);
    lg[r][tt] = acc;
  }
  __syncthreads();
  if (threadIdx.x < 16) {
    int r = threadIdx.x;
    float m = lg[r][0];
#pragma unroll
    for (int tt = 1; tt < 8; ++tt) m = fmaxf(m, lg[r][tt]);
    float ex[8]; float s = 0.f;
#pragma unroll
    for (int tt = 0; tt < 8; ++tt) { ex[tt] = __expf(lg[r][tt] - m); s += ex[tt]; }
    float inv = 1.f / s;
#pragma unroll
    for (int tt = 0; tt < 8; ++tt) att[((size_t)(row0 + r) << 3) + tt] = ex[tt] * inv;
  }
}

// ---- main fused GEMM: out[n][e] += sum_{t in split} att[n][t] * (xf @ w[t]) ----
// 128x128 tile, BK=32, 4 waves of 64x64, t-split over blockIdx.z (2 t's each).
__global__ __launch_bounds__(256) void k_gemm(const u16* __restrict__ abf,
                                              const u16* __restrict__ bt,
                                              const float* __restrict__ att,
                                              float* __restrict__ out) {
  __shared__ u16 lA[128 * 32];
  __shared__ u16 lB[128 * 32];
  __shared__ float lAtt[128][8];

  const int tid  = threadIdx.x;
  const int lane = tid & 63;
  const int w    = tid >> 6;
  const int wr = w >> 1, wc = w & 1;
  const int bm = blockIdx.y * 128, bn = blockIdx.x * 128;
  const int t0 = blockIdx.z * 2;

  { // stage att rows for this M-tile: lAtt[128][8]
    int r = tid >> 1, c = (tid & 1) * 4;
    *(float4*)&lAtt[r][c] = *(const float4*)&att[((size_t)(bm + r) << 3) + c];
  }

  f32x4 acc[4][4] = {};

  const int arow  = lane & 15;        // fragment row/col within 16-block
  const int kof   = (lane >> 4) * 8;  // k offset (shorts) within BK=32
  const int srow  = lane >> 2;        // staging: row within 16-row chunk
  const int sbyte = (lane & 3) * 16;  // staging: byte offset within 64B row

  for (int tl = 0; tl < 2; ++tl) {
    const int t = t0 + tl;
    const u16* bBase = bt + ((size_t)t << 20);
    for (int kk = 0; kk < 1024; kk += 32) {
      __syncthreads();  // previous iter's ds_reads done before overwrite
#pragma unroll
      for (int j = 0; j < 2; ++j) {
        const int ch = w * 2 + j;  // 16-row chunk id (wave-uniform)
        const char* ga = (const char*)(abf + ((size_t)(bm + ch * 16 + srow) << 10) + kk) + sbyte;
        const char* gb = (const char*)(bBase + ((size_t)(bn + ch * 16 + srow) << 10) + kk) + sbyte;
        __builtin_amdgcn_global_load_lds((const AS1 void*)ga, (AS3 void*)((char*)lA + ch * 1024), 16, 0, 0);
        __builtin_amdgcn_global_load_lds((const AS1 void*)gb, (AS3 void*)((char*)lB + ch * 1024), 16, 0, 0);
      }
      __syncthreads();  // staging complete
      bf16x8 a[4], b[4];
#pragma unroll
      for (int m = 0; m < 4; ++m)
        a[m] = *(const bf16x8*)&lA[(wr * 64 + m * 16 + arow) * 32 + kof];
#pragma unroll
      for (int n = 0; n < 4; ++n)
        b[n] = *(const bf16x8*)&lB[(wc * 64 + n * 16 + arow) * 32 + kof];
#pragma unroll
      for (int m = 0; m < 4; ++m)
#pragma unroll
        for (int n = 0; n < 4; ++n)
          acc[m][n] = __builtin_amdgcn_mfma_f32_16x16x32_bf16(a[m], b[n], acc[m][n], 0, 0, 0);
    }
    // fold att_t: ratio trick keeps single accumulator.
    // invariant after segment t (tl==0): acc = att_t*P_t / att_{t+1}
    // after last segment: acc = sum att*P (scaled by att_last)
#pragma unroll
    for (int m = 0; m < 4; ++m)
#pragma unroll
      for (int i = 0; i < 4; ++i) {
        const int rl = wr * 64 + m * 16 + ((lane >> 4) << 2) + i;
        const float s = lAtt[rl][t];
        const float r = (tl == 0) ? (s / lAtt[rl][t + 1]) : s;
#pragma unroll
        for (int n = 0; n < 4; ++n) acc[m][n][i] *= r;
      }
  }

  // epilogue: atomic accumulate across the 4 t-splits (out pre-zeroed)
#pragma unroll
  for (int m = 0; m < 4; ++m) {
    const int row = bm + wr * 64 + m * 16 + ((lane >> 4) << 2);
#pragma unroll
    for (int i = 0; i < 4; ++i)
#pragma unroll
      for (int n = 0; n < 4; ++n) {
        const int col = bn + wc * 64 + n * 16 + arow;
        unsafeAtomicAdd(&out[((size_t)(row + i) << 10) + col], acc[m][n][i]);
      }
  }
}

extern "C" void kernel_launch(void* const* d_in, const int* in_sizes, int n_in,
                              void* d_out, int out_size, void* d_ws, size_t ws_size,
                              hipStream_t stream) {
  (void)in_sizes; (void)n_in; (void)ws_size;
  const float* x      = (const float*)d_in[0];   // (512,8,1024)
  const float* w      = (const float*)d_in[1];   // (8,1024,1024)
  const float* wread  = (const float*)d_in[2];   // (1,1024,16)
  const float* wwrite = (const float*)d_in[3];   // (8,1024,16)
  float* out = (float*)d_out;                    // (512,8,1024) f32

  char* ws = (char*)d_ws;
  u16*   Abf = (u16*)ws;                                   // 8 MiB  bf16 xf
  u16*   BT  = (u16*)(ws + (8ull << 20));                  // 16 MiB bf16 w^T [t][e][d]
  float* W2  = (float*)(ws + (24ull << 20));               // 512 KiB f32 [t][d][16]
  float* att = (float*)(ws + (24ull << 20) + (512ull << 10)); // 128 KiB f32 [n][8]

  k_convert_x<<<4096, 256, 0, stream>>>(x, Abf);
  k_transpose_w<<<dim3(16, 16, 8), 256, 0, stream>>>(w, BT);
  k_w2<<<512, 256, 0, stream>>>(w, wwrite, W2);
  k_att<<<256, 256, 0, stream>>>(x, wread, W2, att);
  hipMemsetAsync(d_out, 0, (size_t)out_size * sizeof(float), stream);
  k_gemm<<<dim3(8, 32, 4), 256, 0, stream>>>(Abf, BT, att, out);
}

// Round 2
// 240.580 us; speedup vs baseline: 1.7525x; 1.7525x over previous
//
#include <hip/hip_runtime.h>
#include <stdint.h>

typedef unsigned short u16;
typedef __attribute__((ext_vector_type(8))) short bf16x8;
typedef __attribute__((ext_vector_type(4))) float f32x4;
typedef __attribute__((ext_vector_type(4))) unsigned short u16x4;

#define AS1 __attribute__((address_space(1)))
#define AS3 __attribute__((address_space(3)))

static __device__ __forceinline__ u16 f2bf(float f) {
  union { float f; uint32_t u; } c; c.f = f;
  return (u16)((c.u + 0x7FFFu + ((c.u >> 16) & 1u)) >> 16);
}

// ---- x (f32) -> bf16, 4 elems/thread ----
__global__ __launch_bounds__(256) void k_convert_x(const float* __restrict__ x,
                                                   u16* __restrict__ abf) {
  int i = blockIdx.x * 256 + threadIdx.x;
  float4 v = reinterpret_cast<const float4*>(x)[i];
  u16x4 o = { f2bf(v.x), f2bf(v.y), f2bf(v.z), f2bf(v.w) };
  reinterpret_cast<u16x4*>(abf)[i] = o;
}

// ---- w[t][d][e] f32 -> bt[t][e][d] bf16 (transpose, 64x64 tiles) ----
__global__ __launch_bounds__(256) void k_transpose_w(const float* __restrict__ w,
                                                     u16* __restrict__ bt) {
  __shared__ u16 tile[64][65];
  const int t = blockIdx.z;
  const int e0 = blockIdx.x * 64, d0 = blockIdx.y * 64;
  const int tx = threadIdx.x & 63, ty = threadIdx.x >> 6;
  const float* wp = w + ((size_t)t << 20);
  u16* bp = bt + ((size_t)t << 20);
  for (int rr = 0; rr < 16; ++rr) {
    int r = rr * 4 + ty;
    tile[r][tx] = f2bf(wp[(size_t)(d0 + r) * 1024 + (e0 + tx)]);
  }
  __syncthreads();
  for (int rr = 0; rr < 16; ++rr) {
    int r = rr * 4 + ty;
    bp[(size_t)(e0 + r) * 1024 + (d0 + tx)] = tile[tx][r];
  }
}

// ---- W2[t] = w[t] @ ww[t]  (1024x1024 @ 1024x16), MFMA, writes BT2[16+t*16+k][d] bf16 ----
// grid (8 d-chunks, 8 t), 256 thr = 4 waves x 32 rows. ww[t] staged transposed in LDS.
__global__ __launch_bounds__(256) void k_w2(const float* __restrict__ w,
                                            const float* __restrict__ ww,
                                            u16* __restrict__ bt2) {
  __shared__ float wwT[16][1028];   // pad 1028: b128 reads ~2-way conflict (free)
  const int tid = threadIdx.x, lane = tid & 63, wv = tid >> 6;
  const int t = blockIdx.y;
  const int d0 = blockIdx.x * 128 + wv * 32;
  const int fr = lane & 15;          // A-row / B-col within fragment
  const int koff = (lane >> 4) * 8;  // k offset within BK=32
  const float* wp = w + ((size_t)t << 20);
  const float* wwp = ww + (t << 14);
  for (int it = 0; it < 64; ++it) {
    int idx = it * 256 + tid;        // 16384 = 1024 e x 16 k
    wwT[idx & 15][idx >> 4] = wwp[idx];
  }
  __syncthreads();
  f32x4 acc[2] = {};
  for (int kk = 0; kk < 1024; kk += 32) {
    const int e0 = kk + koff;
    float4 b0 = *(const float4*)&wwT[fr][e0];
    float4 b1 = *(const float4*)&wwT[fr][e0 + 4];
    bf16x8 b;
    ((u16*)&b)[0] = f2bf(b0.x); ((u16*)&b)[1] = f2bf(b0.y);
    ((u16*)&b)[2] = f2bf(b0.z); ((u16*)&b)[3] = f2bf(b0.w);
    ((u16*)&b)[4] = f2bf(b1.x); ((u16*)&b)[5] = f2bf(b1.y);
    ((u16*)&b)[6] = f2bf(b1.z); ((u16*)&b)[7] = f2bf(b1.w);
#pragma unroll
    for (int m = 0; m < 2; ++m) {
      const float* ap = wp + (size_t)(d0 + m * 16 + fr) * 1024 + e0;
      float4 a0 = *(const float4*)ap;
      float4 a1 = *(const float4*)(ap + 4);
      bf16x8 a;
      ((u16*)&a)[0] = f2bf(a0.x); ((u16*)&a)[1] = f2bf(a0.y);
      ((u16*)&a)[2] = f2bf(a0.z); ((u16*)&a)[3] = f2bf(a0.w);
      ((u16*)&a)[4] = f2bf(a1.x); ((u16*)&a)[5] = f2bf(a1.y);
      ((u16*)&a)[6] = f2bf(a1.z); ((u16*)&a)[7] = f2bf(a1.w);
      acc[m] = __builtin_amdgcn_mfma_f32_16x16x32_bf16(a, b, acc[m], 0, 0, 0);
    }
  }
  // C-frag: col=lane&15 = k, row=(lane>>4)*4+i = d offset. Write B^T layout directly.
#pragma unroll
  for (int m = 0; m < 2; ++m)
#pragma unroll
    for (int i = 0; i < 4; ++i) {
      int d = d0 + m * 16 + ((lane >> 4) << 2) + i;
      bt2[(size_t)(16 + t * 16 + fr) * 1024 + d] = f2bf(acc[m][i]);
    }
}

// ---- w_read[d][c] -> BT2[c][d] bf16 (cols 0..15) ----
__global__ __launch_bounds__(256) void k_wread(const float* __restrict__ wr,
                                               u16* __restrict__ bt2) {
  int i = blockIdx.x * 256 + threadIdx.x;   // 16384, linear over [d][c]
  int d = i >> 4, c = i & 15;
  bt2[(size_t)c * 1024 + d] = f2bf(wr[i]);
}

// ---- P[n][144] = Abf @ BT2^T : MFMA skinny GEMM ----
// grid 64 blocks x 256 thr; wave = 16 rows x 144 cols (9 N-frags).
__global__ __launch_bounds__(256) void k_p(const u16* __restrict__ abf,
                                           const u16* __restrict__ bt2,
                                           float* __restrict__ P) {
  const int tid = threadIdx.x, lane = tid & 63, wv = tid >> 6;
  const int row0 = blockIdx.x * 64 + wv * 16;
  const int fr = lane & 15, koff = (lane >> 4) * 8;
  f32x4 acc[9] = {};
  for (int kk = 0; kk < 1024; kk += 32) {
    bf16x8 a = *(const bf16x8*)&abf[(size_t)(row0 + fr) * 1024 + kk + koff];
#pragma unroll
    for (int n = 0; n < 9; ++n) {
      bf16x8 b = *(const bf16x8*)&bt2[(size_t)(n * 16 + fr) * 1024 + kk + koff];
      acc[n] = __builtin_amdgcn_mfma_f32_16x16x32_bf16(a, b, acc[n], 0, 0, 0);
    }
  }
  const int rbase = row0 + ((lane >> 4) << 2);
#pragma unroll
  for (int n = 0; n < 9; ++n)
#pragma unroll
    for (int i = 0; i < 4; ++i)
      P[(size_t)(rbase + i) * 144 + n * 16 + fr] = acc[n][i];
}

// ---- logits -> softmax -> att[n][8]; 8 threads per row ----
__global__ __launch_bounds__(256) void k_soft(const float* __restrict__ P,
                                              float* __restrict__ att) {
  __shared__ float lg[32][8];
  const int rl = threadIdx.x >> 3, tt = threadIdx.x & 7;
  const int r = blockIdx.x * 32 + rl;
  const float* p = P + (size_t)r * 144;
  float4 x0 = *(const float4*)(p),     x1 = *(const float4*)(p + 4),
         x2 = *(const float4*)(p + 8), x3 = *(const float4*)(p + 12);
  const float* q = p + 16 + tt * 16;
  float4 y0 = *(const float4*)(q),     y1 = *(const float4*)(q + 4),
         y2 = *(const float4*)(q + 8), y3 = *(const float4*)(q + 12);
  float acc = x0.x*y0.x + x0.y*y0.y + x0.z*y0.z + x0.w*y0.w
            + x1.x*y1.x + x1.y*y1.y + x1.z*y1.z + x1.w*y1.w
            + x2.x*y2.x + x2.y*y2.y + x2.z*y2.z + x2.w*y2.w
            + x3.x*y3.x + x3.y*y3.y + x3.z*y3.z + x3.w*y3.w;
  lg[rl][tt] = acc;
  __syncthreads();
  float m = lg[rl][0];
#pragma unroll
  for (int j = 1; j < 8; ++j) m = fmaxf(m, lg[rl][j]);
  float s = 0.f;
#pragma unroll
  for (int j = 0; j < 8; ++j) s += __expf(lg[rl][j] - m);
  att[(size_t)r * 8 + tt] = __expf(lg[rl][tt] - m) / s;
}

// ---- main fused GEMM: out[n][e] += sum_{t in split} att[n][t] * (xf @ w[t]) ----
// 128x128 tile, BK=32, 4 waves of 64x64, t-split over blockIdx.z (2 t's each).
__global__ __launch_bounds__(256) void k_gemm(const u16* __restrict__ abf,
                                              const u16* __restrict__ bt,
                                              const float* __restrict__ att,
                                              float* __restrict__ out) {
  __shared__ u16 lA[128 * 32];
  __shared__ u16 lB[128 * 32];
  __shared__ float lAtt[128][8];

  const int tid  = threadIdx.x;
  const int lane = tid & 63;
  const int w    = tid >> 6;
  const int wr = w >> 1, wc = w & 1;
  const int bm = blockIdx.y * 128, bn = blockIdx.x * 128;
  const int t0 = blockIdx.z * 2;

  { // stage att rows for this M-tile: lAtt[128][8]
    int r = tid >> 1, c = (tid & 1) * 4;
    *(float4*)&lAtt[r][c] = *(const float4*)&att[((size_t)(bm + r) << 3) + c];
  }

  f32x4 acc[4][4] = {};

  const int arow  = lane & 15;        // fragment row/col within 16-block
  const int kof   = (lane >> 4) * 8;  // k offset (shorts) within BK=32
  const int srow  = lane >> 2;        // staging: row within 16-row chunk
  const int sbyte = (lane & 3) * 16;  // staging: byte offset within 64B row

  for (int tl = 0; tl < 2; ++tl) {
    const int t = t0 + tl;
    const u16* bBase = bt + ((size_t)t << 20);
    for (int kk = 0; kk < 1024; kk += 32) {
      __syncthreads();  // previous iter's ds_reads done before overwrite
#pragma unroll
      for (int j = 0; j < 2; ++j) {
        const int ch = w * 2 + j;  // 16-row chunk id (wave-uniform)
        const char* ga = (const char*)(abf + ((size_t)(bm + ch * 16 + srow) << 10) + kk) + sbyte;
        const char* gb = (const char*)(bBase + ((size_t)(bn + ch * 16 + srow) << 10) + kk) + sbyte;
        __builtin_amdgcn_global_load_lds((const AS1 void*)ga, (AS3 void*)((char*)lA + ch * 1024), 16, 0, 0);
        __builtin_amdgcn_global_load_lds((const AS1 void*)gb, (AS3 void*)((char*)lB + ch * 1024), 16, 0, 0);
      }
      __syncthreads();  // staging complete
      bf16x8 a[4], b[4];
#pragma unroll
      for (int m = 0; m < 4; ++m)
        a[m] = *(const bf16x8*)&lA[(wr * 64 + m * 16 + arow) * 32 + kof];
#pragma unroll
      for (int n = 0; n < 4; ++n)
        b[n] = *(const bf16x8*)&lB[(wc * 64 + n * 16 + arow) * 32 + kof];
#pragma unroll
      for (int m = 0; m < 4; ++m)
#pragma unroll
        for (int n = 0; n < 4; ++n)
          acc[m][n] = __builtin_amdgcn_mfma_f32_16x16x32_bf16(a[m], b[n], acc[m][n], 0, 0, 0);
    }
    // fold att_t: ratio trick keeps single accumulator.
#pragma unroll
    for (int m = 0; m < 4; ++m)
#pragma unroll
      for (int i = 0; i < 4; ++i) {
        const int rl = wr * 64 + m * 16 + ((lane >> 4) << 2) + i;
        const float s = lAtt[rl][t];
        const float r = (tl == 0) ? (s / lAtt[rl][t + 1]) : s;
#pragma unroll
        for (int n = 0; n < 4; ++n) acc[m][n][i] *= r;
      }
  }

  // epilogue: atomic accumulate across the 4 t-splits (out pre-zeroed)
#pragma unroll
  for (int m = 0; m < 4; ++m) {
    const int row = bm + wr * 64 + m * 16 + ((lane >> 4) << 2);
#pragma unroll
    for (int i = 0; i < 4; ++i)
#pragma unroll
      for (int n = 0; n < 4; ++n) {
        const int col = bn + wc * 64 + n * 16 + arow;
        unsafeAtomicAdd(&out[((size_t)(row + i) << 10) + col], acc[m][n][i]);
      }
  }
}

extern "C" void kernel_launch(void* const* d_in, const int* in_sizes, int n_in,
                              void* d_out, int out_size, void* d_ws, size_t ws_size,
                              hipStream_t stream) {
  (void)in_sizes; (void)n_in; (void)ws_size;
  const float* x      = (const float*)d_in[0];   // (512,8,1024)
  const float* w      = (const float*)d_in[1];   // (8,1024,1024)
  const float* wread  = (const float*)d_in[2];   // (1,1024,16)
  const float* wwrite = (const float*)d_in[3];   // (8,1024,16)
  float* out = (float*)d_out;                    // (512,8,1024) f32

  char* ws = (char*)d_ws;
  u16*   Abf = (u16*)ws;                         // 8 MiB   bf16 xf
  u16*   BT  = (u16*)(ws + (8ull << 20));        // 16 MiB  bf16 w^T [t][e][d]
  u16*   BT2 = (u16*)(ws + (24ull << 20));       // 288 KiB bf16 [144][1024] = [wread|W2]^T
  float* P   = (float*)(ws + (25ull << 20));     // 2.25 MiB f32 [4096][144]
  float* att = (float*)(ws + (28ull << 20));     // 128 KiB f32 [n][8]

  k_convert_x<<<4096, 256, 0, stream>>>(x, Abf);
  k_transpose_w<<<dim3(16, 16, 8), 256, 0, stream>>>(w, BT);
  k_w2<<<dim3(8, 8), 256, 0, stream>>>(w, wwrite, BT2);
  k_wread<<<64, 256, 0, stream>>>(wread, BT2);
  k_p<<<64, 256, 0, stream>>>(Abf, BT2, P);
  k_soft<<<128, 256, 0, stream>>>(P, att);
  hipMemsetAsync(d_out, 0, (size_t)out_size * sizeof(float), stream);
  k_gemm<<<dim3(8, 32, 4), 256, 0, stream>>>(Abf, BT, att, out);
}

// Round 3
// 160.676 us; speedup vs baseline: 2.6240x; 1.4973x over previous
//
#include <hip/hip_runtime.h>
#include <stdint.h>

typedef unsigned short u16;
typedef __attribute__((ext_vector_type(8))) short bf16x8;
typedef __attribute__((ext_vector_type(4))) float f32x4;
typedef __attribute__((ext_vector_type(4))) unsigned short u16x4;

#define AS1 __attribute__((address_space(1)))
#define AS3 __attribute__((address_space(3)))

static __device__ __forceinline__ u16 f2bf(float f) {
  union { float f; uint32_t u; } c; c.f = f;
  return (u16)((c.u + 0x7FFFu + ((c.u >> 16) & 1u)) >> 16);
}

// ---- x (f32) -> bf16 ----
__global__ __launch_bounds__(256) void k_convert_x(const float* __restrict__ x,
                                                   u16* __restrict__ abf) {
  int i = blockIdx.x * 256 + threadIdx.x;
  float4 v = reinterpret_cast<const float4*>(x)[i];
  u16x4 o = { f2bf(v.x), f2bf(v.y), f2bf(v.z), f2bf(v.w) };
  reinterpret_cast<u16x4*>(abf)[i] = o;
}

// ---- w[t][d][e] f32 -> bt[t][e][d] bf16 ----
__global__ __launch_bounds__(256) void k_transpose_w(const float* __restrict__ w,
                                                     u16* __restrict__ bt) {
  __shared__ u16 tile[64][65];
  const int t = blockIdx.z;
  const int e0 = blockIdx.x * 64, d0 = blockIdx.y * 64;
  const int tx = threadIdx.x & 63, ty = threadIdx.x >> 6;
  const float* wp = w + ((size_t)t << 20);
  u16* bp = bt + ((size_t)t << 20);
  for (int rr = 0; rr < 16; ++rr) {
    int r = rr * 4 + ty;
    tile[r][tx] = f2bf(wp[(size_t)(d0 + r) * 1024 + (e0 + tx)]);
  }
  __syncthreads();
  for (int rr = 0; rr < 16; ++rr) {
    int r = rr * 4 + ty;
    bp[(size_t)(e0 + r) * 1024 + (d0 + tx)] = tile[tx][r];
  }
}

// ---- W2f[t][d][k] += w[t][d,:]·ww[t][:,k] over e-range; MFMA, e-split x4 ----
__global__ __launch_bounds__(256) void k_w2(const float* __restrict__ w,
                                            const float* __restrict__ ww,
                                            float* __restrict__ w2f) {
  __shared__ float wwT[16][264];
  const int tid = threadIdx.x, lane = tid & 63, wv = tid >> 6;
  const int t = blockIdx.y;
  const int d0 = blockIdx.x * 128 + wv * 32;
  const int ez = blockIdx.z * 256;
  const int fr = lane & 15, koff = (lane >> 4) * 8;
  const float* wp = w + ((size_t)t << 20);
  const float* wwp = ww + (t << 14);
  for (int it = 0; it < 16; ++it) {
    int idx = it * 256 + tid;   // 4096 = 256 e x 16 k
    wwT[idx & 15][idx >> 4] = wwp[(size_t)(ez + (idx >> 4)) * 16 + (idx & 15)];
  }
  __syncthreads();
  f32x4 acc[2] = {};
  for (int kk = 0; kk < 256; kk += 32) {
    const int eL = kk + koff;
    float4 b0 = *(const float4*)&wwT[fr][eL];
    float4 b1 = *(const float4*)&wwT[fr][eL + 4];
    bf16x8 b;
    ((u16*)&b)[0] = f2bf(b0.x); ((u16*)&b)[1] = f2bf(b0.y);
    ((u16*)&b)[2] = f2bf(b0.z); ((u16*)&b)[3] = f2bf(b0.w);
    ((u16*)&b)[4] = f2bf(b1.x); ((u16*)&b)[5] = f2bf(b1.y);
    ((u16*)&b)[6] = f2bf(b1.z); ((u16*)&b)[7] = f2bf(b1.w);
#pragma unroll
    for (int m = 0; m < 2; ++m) {
      const float* ap = wp + (size_t)(d0 + m * 16 + fr) * 1024 + ez + eL;
      float4 a0 = *(const float4*)ap;
      float4 a1 = *(const float4*)(ap + 4);
      bf16x8 a;
      ((u16*)&a)[0] = f2bf(a0.x); ((u16*)&a)[1] = f2bf(a0.y);
      ((u16*)&a)[2] = f2bf(a0.z); ((u16*)&a)[3] = f2bf(a0.w);
      ((u16*)&a)[4] = f2bf(a1.x); ((u16*)&a)[5] = f2bf(a1.y);
      ((u16*)&a)[6] = f2bf(a1.z); ((u16*)&a)[7] = f2bf(a1.w);
      acc[m] = __builtin_amdgcn_mfma_f32_16x16x32_bf16(a, b, acc[m], 0, 0, 0);
    }
  }
#pragma unroll
  for (int m = 0; m < 2; ++m)
#pragma unroll
    for (int i = 0; i < 4; ++i) {
      int d = d0 + m * 16 + ((lane >> 4) << 2) + i;
      unsafeAtomicAdd(&w2f[(((size_t)t << 10) + d) * 16 + fr], acc[m][i]);
    }
}

// ---- BT2[144][1024] bf16 = [wread | W2]^T ----
__global__ __launch_bounds__(256) void k_bt2(const float* __restrict__ wread,
                                             const float* __restrict__ w2f,
                                             u16* __restrict__ bt2) {
  int i = blockIdx.x * 256 + threadIdx.x;   // < 147456
  int r = i >> 10, d = i & 1023;
  float v;
  if (r < 16) v = wread[d * 16 + r];
  else { int t = (r - 16) >> 4, k = (r - 16) & 15; v = w2f[(((size_t)t << 10) + d) * 16 + k]; }
  bt2[i] = f2bf(v);
}

// ---- P[n][144] += Abf @ BT2^T over k-range; k-split x4 ----
__global__ __launch_bounds__(256) void k_p(const u16* __restrict__ abf,
                                           const u16* __restrict__ bt2,
                                           float* __restrict__ P) {
  const int tid = threadIdx.x, lane = tid & 63, wv = tid >> 6;
  const int row0 = blockIdx.x * 64 + wv * 16;
  const int k0 = blockIdx.y * 256;
  const int fr = lane & 15, koff = (lane >> 4) * 8;
  f32x4 acc[9] = {};
  for (int kk = 0; kk < 256; kk += 32) {
    bf16x8 a = *(const bf16x8*)&abf[(size_t)(row0 + fr) * 1024 + k0 + kk + koff];
#pragma unroll
    for (int n = 0; n < 9; ++n) {
      bf16x8 b = *(const bf16x8*)&bt2[(size_t)(n * 16 + fr) * 1024 + k0 + kk + koff];
      acc[n] = __builtin_amdgcn_mfma_f32_16x16x32_bf16(a, b, acc[n], 0, 0, 0);
    }
  }
  const int rbase = row0 + ((lane >> 4) << 2);
#pragma unroll
  for (int n = 0; n < 9; ++n)
#pragma unroll
    for (int i = 0; i < 4; ++i)
      unsafeAtomicAdd(&P[(size_t)(rbase + i) * 144 + n * 16 + fr], acc[n][i]);
}

// ---- logits -> softmax -> att[n][8] ----
__global__ __launch_bounds__(256) void k_soft(const float* __restrict__ P,
                                              float* __restrict__ att) {
  __shared__ float lg[32][8];
  const int rl = threadIdx.x >> 3, tt = threadIdx.x & 7;
  const int r = blockIdx.x * 32 + rl;
  const float* p = P + (size_t)r * 144;
  float4 x0 = *(const float4*)(p),     x1 = *(const float4*)(p + 4),
         x2 = *(const float4*)(p + 8), x3 = *(const float4*)(p + 12);
  const float* q = p + 16 + tt * 16;
  float4 y0 = *(const float4*)(q),     y1 = *(const float4*)(q + 4),
         y2 = *(const float4*)(q + 8), y3 = *(const float4*)(q + 12);
  float acc = x0.x*y0.x + x0.y*y0.y + x0.z*y0.z + x0.w*y0.w
            + x1.x*y1.x + x1.y*y1.y + x1.z*y1.z + x1.w*y1.w
            + x2.x*y2.x + x2.y*y2.y + x2.z*y2.z + x2.w*y2.w
            + x3.x*y3.x + x3.y*y3.y + x3.z*y3.z + x3.w*y3.w;
  lg[rl][tt] = acc;
  __syncthreads();
  float m = lg[rl][0];
#pragma unroll
  for (int j = 1; j < 8; ++j) m = fmaxf(m, lg[rl][j]);
  float s = 0.f;
#pragma unroll
  for (int j = 0; j < 8; ++j) s += __expf(lg[rl][j] - m);
  att[(size_t)r * 8 + tt] = __expf(lg[rl][tt] - m) / s;
}

// ======== main GEMM: 256x256 tile, BK=64, 8-phase pipelined schedule ========
// out[n][e] += att-weighted xf @ w[t], t-split z=4 (2 t's/block, ratio fold).
// LDS buf b at b*65536: A0@0, A1@16K, B0@32K, B1@48K, each [128 rows][64 k] bf16.
// Swizzle: granule(16B) column ^= (row&7) on both stage-source and ds_read.
#define BAR()   asm volatile("s_barrier" ::: "memory")
#define LGKM0() asm volatile("s_waitcnt lgkmcnt(0)" ::: "memory")
#define VM6()   asm volatile("s_waitcnt vmcnt(6)" ::: "memory")
#define VM0()   asm volatile("s_waitcnt vmcnt(0)" ::: "memory")

__global__ __launch_bounds__(512, 2) void k_gemm256(const u16* __restrict__ abf,
                                                    const u16* __restrict__ bt,
                                                    const float* __restrict__ att,
                                                    float* __restrict__ out) {
  __shared__ char lds[133120];
  float* lAtt = (float*)(lds + 131072);   // [256][2]

  const int tid = threadIdx.x;
  const int lane = tid & 63;
  const int wv = tid >> 6;            // 0..7
  const int wr = wv >> 2, wc = wv & 3;

  int id = (blockIdx.z * gridDim.y + blockIdx.y) * gridDim.x + blockIdx.x; // 0..255
  int sw = (id & 7) * 32 + (id >> 3);         // XCD chunk swizzle (bijective)
  const int bx = sw & 3, by = (sw >> 2) & 15, bz = sw >> 6;
  const int bm = by * 256, bn = bx * 256, t0 = bz * 2;

  { int r = tid >> 1, c = tid & 1;
    lAtt[r * 2 + c] = att[(size_t)(bm + r) * 8 + t0 + c]; }

  const int l7 = lane & 7, lq = lane >> 4, l15 = lane & 15;
  const int srow = lane >> 3;
  const int scg = l7 ^ srow;                  // pre-swizzled source granule
  const char* Abase = (const char*)abf;
  const char* Bbase = (const char*)bt;
  const size_t aSt0 = (size_t)(bm + wv * 16 + srow) * 2048 + scg * 16;
  const size_t bSt0 = (size_t)(bn + wv * 16 + srow) * 2048 + scg * 16;
  const int sDst = wv * 2048;                 // wave-uniform LDS dest
  const int aRd = (wr * 64 + l15) * 128;
  const int bRd = 32768 + (wc * 32 + l15) * 128;
  const int g0 = ((lq) ^ l7) * 16;            // ks=0 granule
  const int g1 = ((4 + lq) ^ l7) * 16;        // ks=1 granule

#define STAGE_A(bufo, h, tile) do {                                         \
    const char* s_ = Abase + aSt0 + (size_t)(h) * 262144 + ((tile) & 15) * 128; \
    __builtin_amdgcn_global_load_lds((const AS1 void*)s_,                   \
        (AS3 void*)(lds + (bufo) + (h) * 16384 + sDst), 16, 0, 0);          \
    __builtin_amdgcn_global_load_lds((const AS1 void*)(s_ + 16384),         \
        (AS3 void*)(lds + (bufo) + (h) * 16384 + sDst + 1024), 16, 0, 0);   \
  } while (0)
#define STAGE_B(bufo, g, tile) do {                                         \
    const char* s_ = Bbase + (size_t)(t0 + ((tile) >> 4)) * 2097152         \
                   + bSt0 + (size_t)(g) * 262144 + ((tile) & 15) * 128;     \
    __builtin_amdgcn_global_load_lds((const AS1 void*)s_,                   \
        (AS3 void*)(lds + (bufo) + 32768 + (g) * 16384 + sDst), 16, 0, 0);  \
    __builtin_amdgcn_global_load_lds((const AS1 void*)(s_ + 16384),         \
        (AS3 void*)(lds + (bufo) + 32768 + (g) * 16384 + sDst + 1024), 16, 0, 0); \
  } while (0)
#define LDA(bufo, h) do {                                                   \
    const char* p_ = lds + (bufo) + (h) * 16384 + aRd;                      \
    _Pragma("unroll") for (int mm = 0; mm < 4; ++mm) {                      \
      a[mm][0] = *(const bf16x8*)(p_ + mm * 2048 + g0);                     \
      a[mm][1] = *(const bf16x8*)(p_ + mm * 2048 + g1); }                   \
  } while (0)
#define LDB(bufo, g, br) do {                                               \
    const char* p_ = lds + (bufo) + (g) * 16384 + bRd;                      \
    _Pragma("unroll") for (int nn = 0; nn < 2; ++nn) {                      \
      br[nn][0] = *(const bf16x8*)(p_ + nn * 2048 + g0);                    \
      br[nn][1] = *(const bf16x8*)(p_ + nn * 2048 + g1); }                  \
  } while (0)
#define MFQ(h, g, br) do {                                                  \
    __builtin_amdgcn_s_setprio(1);                                          \
    _Pragma("unroll") for (int mm = 0; mm < 4; ++mm)                        \
    _Pragma("unroll") for (int nn = 0; nn < 2; ++nn) {                      \
      acc[(h)*4+mm][(g)*2+nn] = __builtin_amdgcn_mfma_f32_16x16x32_bf16(    \
          a[mm][0], br[nn][0], acc[(h)*4+mm][(g)*2+nn], 0, 0, 0);           \
      acc[(h)*4+mm][(g)*2+nn] = __builtin_amdgcn_mfma_f32_16x16x32_bf16(    \
          a[mm][1], br[nn][1], acc[(h)*4+mm][(g)*2+nn], 0, 0, 0); }         \
    __builtin_amdgcn_s_setprio(0);                                          \
  } while (0)

  f32x4 acc[8][4] = {};
  bf16x8 a[4][2], b0[2][2], b1[2][2];

  // prologue: tile0 -> buf0 (A0,B0,B1,A1), tile1 -> buf1 (A0,B0,B1)
  STAGE_A(0, 0, 0); STAGE_B(0, 0, 0); STAGE_B(0, 1, 0); STAGE_A(0, 1, 0);
  STAGE_A(65536, 0, 1); STAGE_B(65536, 0, 1); STAGE_B(65536, 1, 1);
  VM6(); BAR();

  for (int i = 0; i < 15; ++i) {
    if (i == 8) {   // t-boundary: acc *= att_t0/att_t1 (ratio fold)
#pragma unroll
      for (int m = 0; m < 8; ++m) {
        const int h_ = m >> 2, mm_ = m & 3;
#pragma unroll
        for (int ii = 0; ii < 4; ++ii) {
          const int r_ = h_ * 128 + wr * 64 + mm_ * 16 + lq * 4 + ii;
          const float sc = lAtt[r_ * 2] / lAtt[r_ * 2 + 1];
#pragma unroll
          for (int n = 0; n < 4; ++n) acc[m][n][ii] *= sc;
        }
      }
    }
    const int j1 = 2 * i + 1, j2 = 2 * i + 2, j3 = 2 * i + 3;
    // ph1
    LDA(0, 0); LDB(0, 0, b0); STAGE_A(65536, 1, j1);
    BAR(); LGKM0(); MFQ(0, 0, b0); BAR();
    // ph2
    LDB(0, 1, b1); STAGE_A(0, 0, j2);
    BAR(); LGKM0(); MFQ(0, 1, b1); BAR();
    // ph3
    LDA(0, 1); STAGE_B(0, 0, j2);
    BAR(); LGKM0(); MFQ(1, 1, b1); BAR();
    // ph4
    STAGE_B(0, 1, j2);
    BAR(); MFQ(1, 0, b0); VM6(); BAR();
    // ph5
    LDA(65536, 0); LDB(65536, 0, b0); STAGE_A(0, 1, j2);
    BAR(); LGKM0(); MFQ(0, 0, b0); BAR();
    // ph6
    LDB(65536, 1, b1); STAGE_A(65536, 0, j3);
    BAR(); LGKM0(); MFQ(0, 1, b1); BAR();
    // ph7
    LDA(65536, 1); STAGE_B(65536, 0, j3);
    BAR(); LGKM0(); MFQ(1, 1, b1); BAR();
    // ph8
    STAGE_B(65536, 1, j3);
    BAR(); MFQ(1, 0, b0); VM6(); BAR();
  }
  // peeled last iter (tiles 30,31): only ph1 stages (tile31.A1); drain at ph4
  LDA(0, 0); LDB(0, 0, b0); STAGE_A(65536, 1, 31);
  BAR(); LGKM0(); MFQ(0, 0, b0); BAR();
  LDB(0, 1, b1);
  BAR(); LGKM0(); MFQ(0, 1, b1); BAR();
  LDA(0, 1);
  BAR(); LGKM0(); MFQ(1, 1, b1); BAR();
  BAR(); MFQ(1, 0, b0); VM0(); BAR();
  LDA(65536, 0); LDB(65536, 0, b0);
  BAR(); LGKM0(); MFQ(0, 0, b0); BAR();
  LDB(65536, 1, b1);
  BAR(); LGKM0(); MFQ(0, 1, b1); BAR();
  LDA(65536, 1);
  BAR(); LGKM0(); MFQ(1, 1, b1); BAR();
  BAR(); MFQ(1, 0, b0); BAR();

  // epilogue: scale by att_t1, atomic-accumulate across z-splits
#pragma unroll
  for (int m = 0; m < 8; ++m) {
    const int h_ = m >> 2, mm_ = m & 3;
#pragma unroll
    for (int ii = 0; ii < 4; ++ii) {
      const int rl = h_ * 128 + wr * 64 + mm_ * 16 + lq * 4 + ii;
      const float sc = lAtt[rl * 2 + 1];
      const int row = bm + rl;
#pragma unroll
      for (int n = 0; n < 4; ++n) {
        const int g_ = n >> 1, nn_ = n & 1;
        const int col = bn + g_ * 128 + wc * 32 + nn_ * 16 + l15;
        unsafeAtomicAdd(&out[(size_t)row * 1024 + col], acc[m][n][ii] * sc);
      }
    }
  }
#undef STAGE_A
#undef STAGE_B
#undef LDA
#undef LDB
#undef MFQ
}

extern "C" void kernel_launch(void* const* d_in, const int* in_sizes, int n_in,
                              void* d_out, int out_size, void* d_ws, size_t ws_size,
                              hipStream_t stream) {
  (void)in_sizes; (void)n_in; (void)ws_size;
  const float* x      = (const float*)d_in[0];   // (512,8,1024)
  const float* w      = (const float*)d_in[1];   // (8,1024,1024)
  const float* wread  = (const float*)d_in[2];   // (1,1024,16)
  const float* wwrite = (const float*)d_in[3];   // (8,1024,16)
  float* out = (float*)d_out;                    // (512,8,1024) f32

  char* ws = (char*)d_ws;
  u16*   Abf = (u16*)ws;                                    // 8 MiB
  u16*   BT  = (u16*)(ws + (8ull << 20));                   // 16 MiB
  u16*   BT2 = (u16*)(ws + (24ull << 20));                  // 288 KiB
  float* P   = (float*)(ws + (25ull << 20));                // 2.25 MiB
  float* att = (float*)(ws + (28ull << 20));                // 128 KiB
  float* W2f = (float*)(ws + (28ull << 20) + (128ull << 10)); // 512 KiB

  k_convert_x<<<4096, 256, 0, stream>>>(x, Abf);
  k_transpose_w<<<dim3(16, 16, 8), 256, 0, stream>>>(w, BT);
  hipMemsetAsync(W2f, 0, 8 * 1024 * 16 * sizeof(float), stream);
  hipMemsetAsync(P, 0, 4096 * 144 * sizeof(float), stream);
  k_w2<<<dim3(8, 8, 4), 256, 0, stream>>>(w, wwrite, W2f);
  k_bt2<<<576, 256, 0, stream>>>(wread, W2f, BT2);
  k_p<<<dim3(64, 4), 256, 0, stream>>>(Abf, BT2, P);
  k_soft<<<128, 256, 0, stream>>>(P, att);
  hipMemsetAsync(d_out, 0, (size_t)out_size * sizeof(float), stream);
  k_gemm256<<<dim3(4, 16, 4), 512, 0, stream>>>(Abf, BT, att, out);
}